// Round 16
// baseline (3536.808 us; speedup 1.0000x reference)
//
#include <hip/hip_runtime.h>
#include <math.h>

#define T_ 128
#define B_ 64
#define E_ 300
#define H_ 2048

// ======== geometry ========
// K layout: [0,300) x | [300,320) pad | [320,2368) h -> K1 = 2368 = 74 ksteps of 32
#define K1   2368
#define XKS  10
#define NKS  74
#define APELEMS 19398656ull   // 8192 * 2368 (frag-major packed, elems)
#define BXELEMS 5242880ull    // 128 t * 10 ks * 2 hl * 4 nf * 64 l * 8 j (bf16)
#define BXFBYTES 2621440ull   // 128 t * 10 ks * 4 nf * 64 l * 8 j (fp8 of vhi)
#define BHPING  524288ull     // 64 ks * 16 nf * 64 l * 8 j (shorts per ping)
#define BHFPING 262144ull     // 64 ks * 8 grp * 64 l * 8 j (bytes per ping)
#define LOSCALE 16384.f
#define LOINV   6.103515625e-05f

typedef __attribute__((ext_vector_type(8))) short short8;
typedef __attribute__((ext_vector_type(4))) float float4v;

__device__ __forceinline__ unsigned f2bf(float f) {
    unsigned u = __float_as_uint(f);
    return (u + 0x7FFFu + ((u >> 16) & 1u)) >> 16;
}
__device__ __forceinline__ float bf2f(unsigned b) { return __uint_as_float(b << 16); }

// float -> OCP e4m3fn (RNE-ish; values here are small, clamps defensive)
__device__ __forceinline__ unsigned char f2e4m3(float f) {
    unsigned u = __float_as_uint(f);
    unsigned s = (u >> 31) << 7;
    u &= 0x7FFFFFFFu;
    float a = __uint_as_float(u);
    if (a >= 448.f) return (unsigned char)(s | 0x7E);
    int e = (int)(u >> 23) - 127;
    if (e < -6) {                       // subnormal grid: k * 2^-9
        int k = (int)(a * 512.f + 0.5f);
        return (unsigned char)(s | (k <= 7 ? k : 8));   // k==8 -> 2^-6 normal
    }
    unsigned m = u & 0x7FFFFFu;
    unsigned mr = m + 0x7FFFFu + ((m >> 20) & 1u);
    if (mr >> 23) { mr = 0; e += 1; if (e > 8) return (unsigned char)(s | 0x7E); }
    unsigned mm = (mr >> 20) & 7u;
    if (e == 8 && mm == 7u) return (unsigned char)(s | 0x7E);
    return (unsigned char)(s | ((unsigned)(e + 7) << 3) | mm);
}

__device__ __forceinline__ void gl_lds16(const void* g, void* l) {
    __builtin_amdgcn_global_load_lds(
        (const __attribute__((address_space(1))) unsigned int*)g,
        (__attribute__((address_space(3))) unsigned int*)l, 16, 0, 0);
}

__device__ __forceinline__ float sigm(float x) { return 1.f / (1.f + expf(-x)); }

// ================= prologue kernels =================

__global__ void init2(short* __restrict__ Bh, unsigned char* __restrict__ BhF,
                      float* __restrict__ cb) {
    const int nB = 2 * (int)BHPING;
    const int nF = 2 * (int)BHFPING;
    const int nC = 2 * 2048 * 64;
    int stride = gridDim.x * blockDim.x;
    int i = blockIdx.x * blockDim.x + threadIdx.x;
    for (int idx = i; idx < nB; idx += stride) Bh[idx] = 0;
    for (int idx = i; idx < nF; idx += stride) BhF[idx] = 0;
    for (int idx = i; idx < nC; idx += stride) cb[idx] = 0.f;
}

// frag-major: [rb(64)][ks(74)][mf(8)][l(64)][j(8)]
// element = W[row = rb*128+mf*16+(l&15)][kr = ks*32+(l>>4)*8+j]
__global__ void pack_w(const float* __restrict__ Wih, const float* __restrict__ Whh,
                       short* __restrict__ Ahi, unsigned char* __restrict__ AloF) {
    long long idx = (long long)blockIdx.x * blockDim.x + threadIdx.x;
    if (idx >= (long long)APELEMS) return;
    int j  = (int)(idx & 7);
    int l  = (int)((idx >> 3) & 63);
    int mf = (int)((idx >> 9) & 7);
    int rest = (int)(idx >> 12);
    int ks = rest % 74;
    int rb = rest / 74;
    int row = rb * 128 + mf * 16 + (l & 15);
    int kr  = ks * 32 + (l >> 4) * 8 + j;
    float wv = 0.f;
    if (kr < 300)       wv = Wih[(size_t)row * 300 + kr];
    else if (kr >= 320) wv = Whh[(size_t)row * 2048 + (kr - 320)];
    unsigned hb = f2bf(wv);
    Ahi[idx] = (short)hb;
    AloF[idx] = f2e4m3((wv - bf2f(hb)) * LOSCALE);
}

// packed x bf16: [t][ks(10)][hl(2)][nf4(4)][l(64)][j(8)] ; fp8 vhi: [t][ks][nf4][l][j]
__global__ void pack_x(const int* __restrict__ tokens, const float* __restrict__ embed,
                       short* __restrict__ Bx, unsigned char* __restrict__ BxF) {
    long long idx = (long long)blockIdx.x * blockDim.x + threadIdx.x;
    if (idx >= (long long)BXELEMS) return;
    int j   = (int)(idx & 7);
    int l   = (int)((idx >> 3) & 63);
    int nf4 = (int)((idx >> 9) & 3);
    int hl  = (int)((idx >> 11) & 1);
    int rest = (int)(idx >> 12);
    int ks = rest % 10;
    int tt = rest / 10;
    int b  = nf4 * 16 + (l & 15);
    int kr = ks * 32 + (l >> 4) * 8 + j;
    float v = 0.f;
    if (kr < 300) {
        int tok = tokens[tt * 64 + b];
        v = embed[(size_t)tok * 300 + kr];
    }
    unsigned hb = f2bf(v);
    if (hl) Bx[idx] = (short)f2bf(v - bf2f(hb));
    else {
        Bx[idx] = (short)hb;
        BxF[(((size_t)(tt * 10 + ks) * 4 + nf4) * 64 + l) * 8 + j] = f2e4m3(bf2f(hb));
    }
}

// ================= per-step GEMM (round-16: fp8 lo-term) =====================
// 512 blocks = mb(128, 64 rows) x s(4); 256 threads (4 waves); 2/CU.
// r15 structure (fused loop, single barrier/kstep, vmcnt(0)). Per kstep stages
// {Ahi 4KB bf16, Alo 2KB fp8, Bhi 16KB bf16, Blo 4KB fp8} (26KB buffer).
// hi-term: 16 bf16 MFMA/wave (Ahi x [vhi|vlo] merged). lo-term: 8 fp8 MFMA/wave
// (AloF x vhiF) into SEPARATE acc8, scaled by 2^-14 and added in the epilogue.
// Cuts Alo weight stream 38.8 -> 19.4 MB/step (weights 77.6 -> 58.2).
__global__ __launch_bounds__(256, 2) void gemm_step(
    const short* __restrict__ Ahi, const unsigned char* __restrict__ AloF,
    const short* __restrict__ Bx, const unsigned char* __restrict__ BxF,
    const short* __restrict__ Bh, const unsigned char* __restrict__ BhF,
    float* __restrict__ p, int t)
{
    __shared__ short lds[26624];   // 2 bufs x 26KB = 52 KB
    const int bb = (int)blockIdx.x;
    const int mb = bb >> 2, s = bb & 3;          // mb 0..127 (64-row tiles)
    const int rb = mb >> 1, half = mb & 1;
    const int tid = (int)threadIdx.x;
    const int w = tid >> 6, l = tid & 63;
    const int wm = w >> 1, wn = w & 1;
    const int ping = t & 1;
    const int ks0 = (s < 2) ? s * 19 : 38 + (s - 2) * 18;
    const int nks = (s < 2) ? 19 : 18;
    const short* AhiB = Ahi + (size_t)rb * 74 * 4096 + half * 2048;
    const unsigned char* AloB = AloF + (size_t)rb * 74 * 4096 + half * 2048;
    const short* BhP  = Bh + (size_t)ping * BHPING;
    const unsigned char* BhFP = BhF + (size_t)ping * BHFPING;

    float4v acc[2][4], acc8[2][4];
#pragma unroll
    for (int i = 0; i < 2; ++i)
#pragma unroll
        for (int n = 0; n < 4; ++n) {
            acc[i][n]  = (float4v){0.f, 0.f, 0.f, 0.f};
            acc8[i][n] = (float4v){0.f, 0.f, 0.f, 0.f};
        }

    auto stage = [&](int ks, int buf) {
        short* As = lds + buf * 13312;                 // Ahi: 2048 sh (4KB)
        char*  Al8 = (char*)(As + 2048);               // AloF: 2048 B
        short* Bs = As + 3072;                         // Bhi: 8192 sh (16KB)
        char*  Bl8 = (char*)(As + 11264);              // BloF: 4096 B
        gl_lds16(AhiB + (size_t)ks * 4096 + tid * 8, As + tid * 8);
        if (tid < 128)
            gl_lds16(AloB + (size_t)ks * 4096 + tid * 16, Al8 + tid * 16);
#pragma unroll
        for (int q = 0; q < 4; ++q) {
            const int dsel = q >> 1, hl = q & 1;
            const short* base;
            if (ks < XKS) {
                const int xt = dsel ? (127 - t) : t;
                base = Bx + (size_t)(((xt * 10 + ks) * 2 + hl) * 4) * 512;
            } else {
                base = BhP + (size_t)((ks - 10) * 16 + (dsel * 2 + hl) * 4) * 512;
            }
            gl_lds16(base + tid * 8, Bs + q * 2048 + tid * 8);
        }
        // B lo fp8 (4KB, 1 load/thread)
        const unsigned char* srcl;
        if (ks < XKS) {
            const int dsel = tid >> 7;                 // wave-uniform (waves 0-1 / 2-3)
            const int xt = dsel ? (127 - t) : t;
            srcl = BxF + (size_t)((xt * 10 + ks) * 4) * 512 + (tid & 127) * 16;
        } else {
            srcl = BhFP + (size_t)((ks - 10) * 8) * 512 + tid * 16;
        }
        gl_lds16(srcl, Bl8 + tid * 16);
    };

    stage(ks0, 0);
    for (int it = 0; it < nks; ++it) {
        // single sync: stage(it) landed on all waves; gates buf (it+1)&1 reuse
        asm volatile("s_waitcnt vmcnt(0)" ::: "memory");
        __builtin_amdgcn_s_barrier();
        __builtin_amdgcn_sched_barrier(0);

        short* As = lds + (it & 1) * 13312;
        char*  Al8 = (char*)(As + 2048);
        short* Bs = As + 3072;
        char*  Bl8 = (char*)(As + 11264);
        short8 ah[2], bf[8];
        long   al8[2], bl8[4];
#pragma unroll
        for (int i = 0; i < 2; ++i) {
            ah[i]  = *(const short8*)(As + ((wm * 2 + i) * 64 + l) * 8);
            al8[i] = *(const long*)(Al8 + ((wm * 2 + i) * 64 + l) * 8);
        }
#pragma unroll
        for (int j = 0; j < 8; ++j)
            bf[j] = *(const short8*)(Bs + ((wn * 8 + j) * 64 + l) * 8);
#pragma unroll
        for (int n = 0; n < 4; ++n)
            bl8[n] = *(const long*)(Bl8 + ((wn * 4 + n) * 64 + l) * 8);

        stage(ks0 + it + 1, (it + 1) & 1);   // latency hides under MFMA cluster

        __builtin_amdgcn_s_setprio(1);
#pragma unroll
        for (int i = 0; i < 2; ++i)
#pragma unroll
            for (int h2 = 0; h2 < 2; ++h2)
#pragma unroll
                for (int n = 0; n < 4; ++n)
                    acc[i][n] = __builtin_amdgcn_mfma_f32_16x16x32_bf16(
                        ah[i], bf[h2 * 4 + n], acc[i][n], 0, 0, 0);
#pragma unroll
        for (int i = 0; i < 2; ++i)
#pragma unroll
            for (int n = 0; n < 4; ++n)
                acc8[i][n] = __builtin_amdgcn_mfma_f32_16x16x32_fp8_fp8(
                    al8[i], bl8[n], acc8[i][n], 0, 0, 0);
        __builtin_amdgcn_s_setprio(0);
    }
    asm volatile("s_waitcnt vmcnt(0)" ::: "memory");   // drain tail over-fetch
    __builtin_amdgcn_s_barrier();
    __builtin_amdgcn_sched_barrier(0);

    // epilogue: acc + 2^-14 * acc8 -> full 3-term partial
#pragma unroll
    for (int i = 0; i < 2; ++i)
#pragma unroll
        for (int n = 0; n < 4; ++n)
#pragma unroll
            for (int r = 0; r < 4; ++r) {
                int row = mb * 64 + wm * 32 + i * 16 + (l >> 4) * 4 + r;
                int col = wn * 64 + n * 16 + (l & 15);
                p[((size_t)s * 8192 + row) * 128 + col] =
                    acc[i][n][r] + acc8[i][n][r] * LOINV;
            }
}

// ================= per-step update (4 partials) =================
__global__ __launch_bounds__(256) void update2(
    const float* __restrict__ p,
    const float* __restrict__ b_ih, const float* __restrict__ b_hh,
    const int* __restrict__ lens,
    float* __restrict__ cbuf,       // [dir][2048][64] f32
    short* __restrict__ Bh, unsigned char* __restrict__ BhF,
    float* __restrict__ out, int t)
{
    int tid0 = blockIdx.x * 256 + threadIdx.x;
    for (int item = tid0; item < 262144; item += 65536) {
        int b = item & 63, k = (item >> 6) & 2047, dir = item >> 17;
        float g[4];
#pragma unroll
        for (int gg = 0; gg < 4; ++gg) {
            int row = gg * 2048 + k;
            float v = 0.f;
#pragma unroll
            for (int s = 0; s < 4; ++s) v += p[((size_t)s * 8192 + row) * 128 + dir * 64 + b];
            g[gg] = v + b_ih[row] + b_hh[row];
        }
        float iv = sigm(g[0]);
        float fv = sigm(g[1]);
        float gv = tanhf(g[2]);
        float ov = sigm(g[3]);
        size_t cidx = ((size_t)dir * 2048 + k) * 64 + b;
        float c = fv * cbuf[cidx] + iv * gv;
        cbuf[cidx] = c;
        float h = ov * tanhf(c);

        int kk = k & 31, ksh = k >> 5;
        int jj = kk & 7, ll = (kk >> 3) * 16 + (b & 15), sub = b >> 4;
        int pingW = (t + 1) & 1;
        size_t baseh = (size_t)pingW * BHPING + ((size_t)ksh * 16 + (dir * 2) * 4 + sub) * 512 + ll * 8 + jj;
        size_t basel = (size_t)pingW * BHPING + ((size_t)ksh * 16 + (dir * 2 + 1) * 4 + sub) * 512 + ll * 8 + jj;
        unsigned hb = f2bf(h);
        Bh[baseh] = (short)hb;
        Bh[basel] = (short)f2bf(h - bf2f(hb));
        BhF[(size_t)pingW * BHFPING + ((size_t)ksh * 8 + dir * 4 + sub) * 512 + ll * 8 + jj]
            = f2e4m3(bf2f(hb));

        if (dir == 0) { if (t == lens[b] - 1) out[(size_t)b * 4096 + k] = h; }
        else          { if (t == 127)         out[(size_t)b * 4096 + 2048 + k] = h; }
    }
}

// ================= round-1 fallback path (small ws) =================
__global__ void init_state(float* __restrict__ hbuf, float* __restrict__ cbuf) {
    int n_h = 2 * 2 * H_ * B_;
    int n_c = 2 * H_ * B_;
    int stride = gridDim.x * blockDim.x;
    int i = blockIdx.x * blockDim.x + threadIdx.x;
    for (int idx = i; idx < n_h; idx += stride) hbuf[idx] = 0.f;
    for (int idx = i; idx < n_c; idx += stride) cbuf[idx] = 0.f;
}

__global__ void gather_x(const int* __restrict__ tokens, const float* __restrict__ embed,
                         float* __restrict__ x_t) {
    int idx = blockIdx.x * blockDim.x + threadIdx.x;
    int total = T_ * E_ * B_;
    if (idx >= total) return;
    int b = idx % B_;
    int r = idx / B_;
    int e = r % E_;
    int t = r / E_;
    int tok = tokens[t * B_ + b];
    x_t[idx] = embed[tok * E_ + e];
}

__global__ __launch_bounds__(256) void lstm_step(
    const float* __restrict__ x_t, const float* __restrict__ W_ih,
    const float* __restrict__ W_hh, const float* __restrict__ b_ih,
    const float* __restrict__ b_hh, const int* __restrict__ lens,
    const float* __restrict__ h_in, float* __restrict__ h_out,
    float* __restrict__ cbuf, float* __restrict__ out, int t)
{
    const int dir = blockIdx.x >> 8;
    const int kblk = blockIdx.x & 255;
    const int bpair = threadIdx.x & 31;
    const int kloc = threadIdx.x >> 5;
    const int k = kblk * 8 + kloc;
    const int b0 = bpair * 2;
    const int xt = dir ? (T_ - 1 - t) : t;
    const float* xrow = x_t + (size_t)xt * E_ * B_;
    const float* hrow = h_in + (size_t)dir * H_ * B_;
    float a0x = 0.f, a0y = 0.f, a1x = 0.f, a1y = 0.f;
    float a2x = 0.f, a2y = 0.f, a3x = 0.f, a3y = 0.f;
    {
        const float* w0 = W_ih + (size_t)(0 * H_ + k) * E_;
        const float* w1 = W_ih + (size_t)(1 * H_ + k) * E_;
        const float* w2 = W_ih + (size_t)(2 * H_ + k) * E_;
        const float* w3 = W_ih + (size_t)(3 * H_ + k) * E_;
#pragma unroll 4
        for (int kk = 0; kk < E_; ++kk) {
            float2 xv = *(const float2*)(xrow + kk * B_ + b0);
            float c0 = w0[kk], c1 = w1[kk], c2 = w2[kk], c3 = w3[kk];
            a0x += xv.x * c0; a0y += xv.y * c0;
            a1x += xv.x * c1; a1y += xv.y * c1;
            a2x += xv.x * c2; a2y += xv.y * c2;
            a3x += xv.x * c3; a3y += xv.y * c3;
        }
    }
    {
        const float* w0 = W_hh + (size_t)(0 * H_ + k) * H_;
        const float* w1 = W_hh + (size_t)(1 * H_ + k) * H_;
        const float* w2 = W_hh + (size_t)(2 * H_ + k) * H_;
        const float* w3 = W_hh + (size_t)(3 * H_ + k) * H_;
#pragma unroll 4
        for (int kk = 0; kk < H_; ++kk) {
            float2 hv = *(const float2*)(hrow + kk * B_ + b0);
            float c0 = w0[kk], c1 = w1[kk], c2 = w2[kk], c3 = w3[kk];
            a0x += hv.x * c0; a0y += hv.y * c0;
            a1x += hv.x * c1; a1y += hv.y * c1;
            a2x += hv.x * c2; a2y += hv.y * c2;
            a3x += hv.x * c3; a3y += hv.y * c3;
        }
    }
    const int j0 = 0 * H_ + k, j1 = 1 * H_ + k, j2 = 2 * H_ + k, j3 = 3 * H_ + k;
    const float bi = b_ih[j0] + b_hh[j0];
    const float bf = b_ih[j1] + b_hh[j1];
    const float bg = b_ih[j2] + b_hh[j2];
    const float bo = b_ih[j3] + b_hh[j3];
    float* cdir = cbuf + (size_t)dir * H_ * B_;
    float* hdir = h_out + (size_t)dir * H_ * B_;
#pragma unroll
    for (int s = 0; s < 2; ++s) {
        const int b = b0 + s;
        const float ai = (s == 0) ? a0x : a0y;
        const float af = (s == 0) ? a1x : a1y;
        const float ag = (s == 0) ? a2x : a2y;
        const float ao = (s == 0) ? a3x : a3y;
        const float iv = sigm(ai + bi);
        const float fv = sigm(af + bf);
        const float gv = tanhf(ag + bg);
        const float ov = sigm(ao + bo);
        const int sidx = k * B_ + b;
        const float c_old = cdir[sidx];
        const float c_new = fv * c_old + iv * gv;
        cdir[sidx] = c_new;
        const float h_new = ov * tanhf(c_new);
        hdir[sidx] = h_new;
        if (dir == 0) {
            if (t == lens[b] - 1) out[(size_t)b * (2 * H_) + k] = h_new;
        } else {
            if (t == T_ - 1) out[(size_t)b * (2 * H_) + H_ + k] = h_new;
        }
    }
}

// ================= launch =================
extern "C" void kernel_launch(void* const* d_in, const int* in_sizes, int n_in,
                              void* d_out, int out_size, void* d_ws, size_t ws_size,
                              hipStream_t stream) {
    const int*   tokens = (const int*)d_in[0];
    const int*   lens   = (const int*)d_in[1];
    const float* embed  = (const float*)d_in[2];
    const float* W_ih   = (const float*)d_in[3];
    const float* W_hh   = (const float*)d_in[4];
    const float* b_ih   = (const float*)d_in[5];
    const float* b_hh   = (const float*)d_in[6];
    float* out = (float*)d_out;

    // ---- main-path workspace layout (16B-aligned sections) ----
    short* Ahi = (short*)d_ws;                                  // 38.8 MB
    unsigned char* AloF = (unsigned char*)(Ahi + APELEMS);      // 19.4 MB
    short* BxP = (short*)(AloF + APELEMS);                      // 10.5 MB
    unsigned char* BxF = (unsigned char*)(BxP + BXELEMS);       // 2.6 MB
    short* BhP = (short*)(BxF + BXFBYTES);                      // 2.0 MB
    unsigned char* BhF = (unsigned char*)(BhP + 2 * BHPING);    // 0.5 MB
    float* cb2n = (float*)(BhF + 2 * BHFPING);                  // 1.0 MB
    float* pP   = cb2n + 262144;                                // [4][8192][128] 16.8 MB
    const size_t req_new = (size_t)((char*)(pP + 4194304) - (char*)d_ws);

    // ---- round-1 fallback layout (~13 MB) ----
    float* ws   = (float*)d_ws;
    float* x_t  = ws;
    float* hbuf1 = x_t + (size_t)T_ * E_ * B_;
    float* cbuf1 = hbuf1 + (size_t)2 * 2 * H_ * B_;

    if (ws_size >= req_new) {
        init2<<<512, 256, 0, stream>>>(BhP, BhF, cb2n);
        pack_w<<<(int)((APELEMS + 255) / 256), 256, 0, stream>>>(W_ih, W_hh, Ahi, AloF);
        pack_x<<<(int)((BXELEMS + 255) / 256), 256, 0, stream>>>(tokens, embed, BxP, BxF);
        for (int t = 0; t < T_; ++t) {
            gemm_step<<<512, 256, 0, stream>>>(Ahi, AloF, BxP, BxF, BhP, BhF, pP, t);
            update2<<<256, 256, 0, stream>>>(pP, b_ih, b_hh, lens, cb2n, BhP, BhF, out, t);
        }
    } else {
        init_state<<<256, 256, 0, stream>>>(hbuf1, cbuf1);
        {
            int total = T_ * E_ * B_;
            gather_x<<<(total + 255) / 256, 256, 0, stream>>>(tokens, embed, x_t);
        }
        for (int t = 0; t < T_; ++t) {
            const float* h_in  = hbuf1 + (size_t)(t & 1) * 2 * H_ * B_;
            float*       h_out = hbuf1 + (size_t)((t + 1) & 1) * 2 * H_ * B_;
            lstm_step<<<512, 256, 0, stream>>>(x_t, W_ih, W_hh, b_ih, b_hh, lens,
                                               h_in, h_out, cbuf1, out, t);
        }
    }
}

// Round 17
// 3394.484 us; speedup vs baseline: 1.0419x; 1.0419x over previous
//
#include <hip/hip_runtime.h>
#include <math.h>

#define T_ 128
#define B_ 64
#define E_ 300
#define H_ 2048

// ======== geometry ========
// K layout: [0,300) x | [300,320) pad | [320,2368) h -> K1 = 2368 = 74 ksteps of 32
#define K1   2368
#define XKS  10
#define NKS  74
#define APELEMS 19398656ull   // 8192 * 2368 per weight matrix (frag-major packed)
#define BXELEMS 5242880ull    // 128 t * 10 ks * 2 hl * 4 nf * 64 l * 8 j
#define BHPING  524288ull     // 64 ks * 16 nf * 64 l * 8 j (shorts per ping)

typedef __attribute__((ext_vector_type(8))) short short8;
typedef __attribute__((ext_vector_type(4))) float float4v;

__device__ __forceinline__ unsigned f2bf(float f) {
    unsigned u = __float_as_uint(f);
    return (u + 0x7FFFu + ((u >> 16) & 1u)) >> 16;
}
__device__ __forceinline__ float bf2f(unsigned b) { return __uint_as_float(b << 16); }

__device__ __forceinline__ void gl_lds16(const void* g, void* l) {
    __builtin_amdgcn_global_load_lds(
        (const __attribute__((address_space(1))) unsigned int*)g,
        (__attribute__((address_space(3))) unsigned int*)l, 16, 0, 0);
}

__device__ __forceinline__ float sigm(float x) { return 1.f / (1.f + expf(-x)); }

// ================= prologue kernels =================

__global__ void init2(short* __restrict__ Bh, float* __restrict__ cb) {
    const int nB = 2 * (int)BHPING;
    const int nC = 2 * 2048 * 64;
    int stride = gridDim.x * blockDim.x;
    int i = blockIdx.x * blockDim.x + threadIdx.x;
    for (int idx = i; idx < nB; idx += stride) Bh[idx] = 0;
    for (int idx = i; idx < nC; idx += stride) cb[idx] = 0.f;
}

// frag-major packed weights: [rb(64)][ks(74)][mf(8)][l(64)][j(8)]
// element = W[row = rb*128+mf*16+(l&15)][kr = ks*32+(l>>4)*8+j]
__global__ void pack_w(const float* __restrict__ Wih, const float* __restrict__ Whh,
                       short* __restrict__ Ahi, short* __restrict__ Alo) {
    long long idx = (long long)blockIdx.x * blockDim.x + threadIdx.x;
    if (idx >= (long long)APELEMS) return;
    int j  = (int)(idx & 7);
    int l  = (int)((idx >> 3) & 63);
    int mf = (int)((idx >> 9) & 7);
    int rest = (int)(idx >> 12);
    int ks = rest % 74;
    int rb = rest / 74;
    int row = rb * 128 + mf * 16 + (l & 15);
    int kr  = ks * 32 + (l >> 4) * 8 + j;
    float wv = 0.f;
    if (kr < 300)       wv = Wih[(size_t)row * 300 + kr];
    else if (kr >= 320) wv = Whh[(size_t)row * 2048 + (kr - 320)];
    unsigned hb = f2bf(wv);
    Ahi[idx] = (short)hb;
    Alo[idx] = (short)f2bf(wv - bf2f(hb));
}

// packed x: [t(128)][ks(10)][hl(2)][nf4(4)][l(64)][j(8)]
__global__ void pack_x(const int* __restrict__ tokens, const float* __restrict__ embed,
                       short* __restrict__ Bx) {
    long long idx = (long long)blockIdx.x * blockDim.x + threadIdx.x;
    if (idx >= (long long)BXELEMS) return;
    int j   = (int)(idx & 7);
    int l   = (int)((idx >> 3) & 63);
    int nf4 = (int)((idx >> 9) & 3);
    int hl  = (int)((idx >> 11) & 1);
    int rest = (int)(idx >> 12);
    int ks = rest % 10;
    int tt = rest / 10;
    int b  = nf4 * 16 + (l & 15);
    int kr = ks * 32 + (l >> 4) * 8 + j;
    float v = 0.f;
    if (kr < 300) {
        int tok = tokens[tt * 64 + b];
        v = embed[(size_t)tok * 300 + kr];
    }
    unsigned hb = f2bf(v);
    Bx[idx] = hl ? (short)f2bf(v - bf2f(hb)) : (short)hb;
}

// ================= per-step GEMM (round-17: 3-buf counted vmcnt) ============
// 512 blocks = mb(128, 64 rows each) x s(4); 256 threads (4 waves); 2/CU.
// r15 fused 3-term loop, single barrier/kstep. Round-17: 3 LDS buffers and a
// COUNTED wait: stage = uniform 6 loads/thread, so s_waitcnt vmcnt(6) at the
// iteration top waits only for the tile issued TWO iterations ago (latency
// fully covered; 12 loads in steady flight). Buffer hazard: buf (it+2)%3 was
// last READ at iter it-1; those ds_reads complete before that iter's MFMAs,
// which precede the iter-it barrier -> no wave stages over unread data.
// Tail over-fetch UNCLAMPED (lands in adjacent ws buffers, never consumed).
__global__ __launch_bounds__(256, 2) void gemm_step(
    const short* __restrict__ Ahi, const short* __restrict__ Alo,
    const short* __restrict__ Bx, const short* __restrict__ Bh,
    float* __restrict__ p, int t)
{
    __shared__ short lds[36864];   // 3 bufs x 24KB = 72 KB
    const int bb = (int)blockIdx.x;
    const int mb = bb >> 2, s = bb & 3;          // mb 0..127 (64-row tiles)
    const int rb = mb >> 1, half = mb & 1;
    const int tid = (int)threadIdx.x;
    const int w = tid >> 6, l = tid & 63;
    const int wm = w >> 1, wn = w & 1;
    const int ping = t & 1;
    const int ks0 = (s < 2) ? s * 19 : 38 + (s - 2) * 18;
    const int nks = (s < 2) ? 19 : 18;
    const short* AhiB = Ahi + (size_t)rb * 74 * 4096 + half * 2048;
    const short* AloB = Alo + (size_t)rb * 74 * 4096 + half * 2048;
    const short* BhP  = Bh + (size_t)ping * BHPING;

    float4v acc[2][4];
#pragma unroll
    for (int i = 0; i < 2; ++i)
#pragma unroll
        for (int n = 0; n < 4; ++n) acc[i][n] = (float4v){0.f, 0.f, 0.f, 0.f};

    auto stage = [&](int ks, int buf) {
        short* As = lds + buf * 12288;     // Ahi: 2048 shorts (4KB)
        short* Al = As + 2048;             // Alo: 2048 shorts (4KB)
        short* Bs = As + 4096;             // B:   8192 shorts (16KB)
        gl_lds16(AhiB + (size_t)ks * 4096 + tid * 8, As + tid * 8);
        gl_lds16(AloB + (size_t)ks * 4096 + tid * 8, Al + tid * 8);
#pragma unroll
        for (int q = 0; q < 4; ++q) {
            const int dsel = q >> 1, hl = q & 1;
            const short* base;
            if (ks < XKS) {
                const int xt = dsel ? (127 - t) : t;
                base = Bx + (size_t)(((xt * 10 + ks) * 2 + hl) * 4) * 512;
            } else {
                base = BhP + (size_t)((ks - 10) * 16 + (dsel * 2 + hl) * 4) * 512;
            }
            gl_lds16(base + tid * 8, Bs + q * 2048 + tid * 8);
        }
    };

    // prologue: tiles 0,1 in flight (12 loads)
    stage(ks0, 0);
    stage(ks0 + 1, 1);
    for (int it = 0; it < nks; ++it) {
        // counted wait: tile it landed (tile it+1's 6 loads stay in flight)
        asm volatile("s_waitcnt vmcnt(6)" ::: "memory");
        __builtin_amdgcn_s_barrier();
        __builtin_amdgcn_sched_barrier(0);

        short* As = lds + (it % 3) * 12288;
        short* Al = As + 2048;
        short* Bs = As + 4096;
        short8 ah[2], al[2], bf[8];
#pragma unroll
        for (int i = 0; i < 2; ++i) {
            ah[i] = *(const short8*)(As + ((wm * 2 + i) * 64 + l) * 8);
            al[i] = *(const short8*)(Al + ((wm * 2 + i) * 64 + l) * 8);
        }
#pragma unroll
        for (int j = 0; j < 8; ++j)
            bf[j] = *(const short8*)(Bs + ((wn * 8 + j) * 64 + l) * 8);

        stage(ks0 + it + 2, (it + 2) % 3);   // 2-deep prefetch; unclamped tail

        __builtin_amdgcn_s_setprio(1);
#pragma unroll
        for (int i = 0; i < 2; ++i)
#pragma unroll
            for (int h2 = 0; h2 < 2; ++h2)
#pragma unroll
                for (int n = 0; n < 4; ++n)
                    acc[i][n] = __builtin_amdgcn_mfma_f32_16x16x32_bf16(
                        ah[i], bf[h2 * 4 + n], acc[i][n], 0, 0, 0);
#pragma unroll
        for (int i = 0; i < 2; ++i)
#pragma unroll
            for (int n = 0; n < 4; ++n)
                acc[i][n] = __builtin_amdgcn_mfma_f32_16x16x32_bf16(
                    al[i], bf[n], acc[i][n], 0, 0, 0);   // bf[0..3] = vhi of dsel=wn
        __builtin_amdgcn_s_setprio(0);
    }
    asm volatile("s_waitcnt vmcnt(0)" ::: "memory");   // drain tail over-fetch
    __builtin_amdgcn_s_barrier();
    __builtin_amdgcn_sched_barrier(0);

    // epilogue: full 3-term partial for this (64-row, k-quarter) tile
#pragma unroll
    for (int i = 0; i < 2; ++i)
#pragma unroll
        for (int n = 0; n < 4; ++n)
#pragma unroll
            for (int r = 0; r < 4; ++r) {
                int row = mb * 64 + wm * 32 + i * 16 + (l >> 4) * 4 + r;
                int col = wn * 64 + n * 16 + (l & 15);
                p[((size_t)s * 8192 + row) * 128 + col] = acc[i][n][r];
            }
}

// ================= per-step update (4 partials) =================
__global__ __launch_bounds__(256) void update2(
    const float* __restrict__ p,
    const float* __restrict__ b_ih, const float* __restrict__ b_hh,
    const int* __restrict__ lens,
    float* __restrict__ cbuf,       // [dir][2048][64] f32
    short* __restrict__ Bh,         // packed h hi/lo
    float* __restrict__ out, int t)
{
    int tid0 = blockIdx.x * 256 + threadIdx.x;
    for (int item = tid0; item < 262144; item += 65536) {
        int b = item & 63, k = (item >> 6) & 2047, dir = item >> 17;
        float g[4];
#pragma unroll
        for (int gg = 0; gg < 4; ++gg) {
            int row = gg * 2048 + k;
            float v = 0.f;
#pragma unroll
            for (int s = 0; s < 4; ++s) v += p[((size_t)s * 8192 + row) * 128 + dir * 64 + b];
            g[gg] = v + b_ih[row] + b_hh[row];
        }
        float iv = sigm(g[0]);
        float fv = sigm(g[1]);
        float gv = tanhf(g[2]);
        float ov = sigm(g[3]);
        size_t cidx = ((size_t)dir * 2048 + k) * 64 + b;
        float c = fv * cbuf[cidx] + iv * gv;
        cbuf[cidx] = c;
        float h = ov * tanhf(c);

        int kk = k & 31, ksh = k >> 5;
        int jj = kk & 7, ll = (kk >> 3) * 16 + (b & 15), sub = b >> 4;
        int pingW = (t + 1) & 1;
        size_t baseh = (size_t)pingW * BHPING + ((size_t)ksh * 16 + (dir * 2) * 4 + sub) * 512 + ll * 8 + jj;
        size_t basel = (size_t)pingW * BHPING + ((size_t)ksh * 16 + (dir * 2 + 1) * 4 + sub) * 512 + ll * 8 + jj;
        unsigned hb = f2bf(h);
        Bh[baseh] = (short)hb;
        Bh[basel] = (short)f2bf(h - bf2f(hb));

        if (dir == 0) { if (t == lens[b] - 1) out[(size_t)b * 4096 + k] = h; }
        else          { if (t == 127)         out[(size_t)b * 4096 + 2048 + k] = h; }
    }
}

// ================= round-1 fallback path (small ws) =================
__global__ void init_state(float* __restrict__ hbuf, float* __restrict__ cbuf) {
    int n_h = 2 * 2 * H_ * B_;
    int n_c = 2 * H_ * B_;
    int stride = gridDim.x * blockDim.x;
    int i = blockIdx.x * blockDim.x + threadIdx.x;
    for (int idx = i; idx < n_h; idx += stride) hbuf[idx] = 0.f;
    for (int idx = i; idx < n_c; idx += stride) cbuf[idx] = 0.f;
}

__global__ void gather_x(const int* __restrict__ tokens, const float* __restrict__ embed,
                         float* __restrict__ x_t) {
    int idx = blockIdx.x * blockDim.x + threadIdx.x;
    int total = T_ * E_ * B_;
    if (idx >= total) return;
    int b = idx % B_;
    int r = idx / B_;
    int e = r % E_;
    int t = r / E_;
    int tok = tokens[t * B_ + b];
    x_t[idx] = embed[tok * E_ + e];
}

__global__ __launch_bounds__(256) void lstm_step(
    const float* __restrict__ x_t, const float* __restrict__ W_ih,
    const float* __restrict__ W_hh, const float* __restrict__ b_ih,
    const float* __restrict__ b_hh, const int* __restrict__ lens,
    const float* __restrict__ h_in, float* __restrict__ h_out,
    float* __restrict__ cbuf, float* __restrict__ out, int t)
{
    const int dir = blockIdx.x >> 8;
    const int kblk = blockIdx.x & 255;
    const int bpair = threadIdx.x & 31;
    const int kloc = threadIdx.x >> 5;
    const int k = kblk * 8 + kloc;
    const int b0 = bpair * 2;
    const int xt = dir ? (T_ - 1 - t) : t;
    const float* xrow = x_t + (size_t)xt * E_ * B_;
    const float* hrow = h_in + (size_t)dir * H_ * B_;
    float a0x = 0.f, a0y = 0.f, a1x = 0.f, a1y = 0.f;
    float a2x = 0.f, a2y = 0.f, a3x = 0.f, a3y = 0.f;
    {
        const float* w0 = W_ih + (size_t)(0 * H_ + k) * E_;
        const float* w1 = W_ih + (size_t)(1 * H_ + k) * E_;
        const float* w2 = W_ih + (size_t)(2 * H_ + k) * E_;
        const float* w3 = W_ih + (size_t)(3 * H_ + k) * E_;
#pragma unroll 4
        for (int kk = 0; kk < E_; ++kk) {
            float2 xv = *(const float2*)(xrow + kk * B_ + b0);
            float c0 = w0[kk], c1 = w1[kk], c2 = w2[kk], c3 = w3[kk];
            a0x += xv.x * c0; a0y += xv.y * c0;
            a1x += xv.x * c1; a1y += xv.y * c1;
            a2x += xv.x * c2; a2y += xv.y * c2;
            a3x += xv.x * c3; a3y += xv.y * c3;
        }
    }
    {
        const float* w0 = W_hh + (size_t)(0 * H_ + k) * H_;
        const float* w1 = W_hh + (size_t)(1 * H_ + k) * H_;
        const float* w2 = W_hh + (size_t)(2 * H_ + k) * H_;
        const float* w3 = W_hh + (size_t)(3 * H_ + k) * H_;
#pragma unroll 4
        for (int kk = 0; kk < H_; ++kk) {
            float2 hv = *(const float2*)(hrow + kk * B_ + b0);
            float c0 = w0[kk], c1 = w1[kk], c2 = w2[kk], c3 = w3[kk];
            a0x += hv.x * c0; a0y += hv.y * c0;
            a1x += hv.x * c1; a1y += hv.y * c1;
            a2x += hv.x * c2; a2y += hv.y * c2;
            a3x += hv.x * c3; a3y += hv.y * c3;
        }
    }
    const int j0 = 0 * H_ + k, j1 = 1 * H_ + k, j2 = 2 * H_ + k, j3 = 3 * H_ + k;
    const float bi = b_ih[j0] + b_hh[j0];
    const float bf = b_ih[j1] + b_hh[j1];
    const float bg = b_ih[j2] + b_hh[j2];
    const float bo = b_ih[j3] + b_hh[j3];
    float* cdir = cbuf + (size_t)dir * H_ * B_;
    float* hdir = h_out + (size_t)dir * H_ * B_;
#pragma unroll
    for (int s = 0; s < 2; ++s) {
        const int b = b0 + s;
        const float ai = (s == 0) ? a0x : a0y;
        const float af = (s == 0) ? a1x : a1y;
        const float ag = (s == 0) ? a2x : a2y;
        const float ao = (s == 0) ? a3x : a3y;
        const float iv = sigm(ai + bi);
        const float fv = sigm(af + bf);
        const float gv = tanhf(ag + bg);
        const float ov = sigm(ao + bo);
        const int sidx = k * B_ + b;
        const float c_old = cdir[sidx];
        const float c_new = fv * c_old + iv * gv;
        cdir[sidx] = c_new;
        const float h_new = ov * tanhf(c_new);
        hdir[sidx] = h_new;
        if (dir == 0) {
            if (t == lens[b] - 1) out[(size_t)b * (2 * H_) + k] = h_new;
        } else {
            if (t == T_ - 1) out[(size_t)b * (2 * H_) + H_ + k] = h_new;
        }
    }
}

// ================= launch =================
extern "C" void kernel_launch(void* const* d_in, const int* in_sizes, int n_in,
                              void* d_out, int out_size, void* d_ws, size_t ws_size,
                              hipStream_t stream) {
    const int*   tokens = (const int*)d_in[0];
    const int*   lens   = (const int*)d_in[1];
    const float* embed  = (const float*)d_in[2];
    const float* W_ih   = (const float*)d_in[3];
    const float* W_hh   = (const float*)d_in[4];
    const float* b_ih   = (const float*)d_in[5];
    const float* b_hh   = (const float*)d_in[6];
    float* out = (float*)d_out;

    // ---- main-path workspace layout ----
    short* Ahi = (short*)d_ws;
    short* Alo = Ahi + APELEMS;
    short* BxP = Alo + APELEMS;
    short* BhP = BxP + BXELEMS;
    float* cb2n = (float*)(BhP + 2 * BHPING);
    float* pP   = cb2n + 262144;                 // [4][8192][128] f32
    const size_t req_new = (size_t)((char*)(pP + 4194304) - (char*)d_ws);

    // ---- round-1 fallback layout (~13 MB) ----
    float* ws   = (float*)d_ws;
    float* x_t  = ws;
    float* hbuf1 = x_t + (size_t)T_ * E_ * B_;
    float* cbuf1 = hbuf1 + (size_t)2 * 2 * H_ * B_;

    if (ws_size >= req_new) {
        init2<<<512, 256, 0, stream>>>(BhP, cb2n);
        pack_w<<<(int)((APELEMS + 255) / 256), 256, 0, stream>>>(W_ih, W_hh, Ahi, Alo);
        pack_x<<<(int)((BXELEMS + 255) / 256), 256, 0, stream>>>(tokens, embed, BxP);
        for (int t = 0; t < T_; ++t) {
            gemm_step<<<512, 256, 0, stream>>>(Ahi, Alo, BxP, BhP, pP, t);
            update2<<<256, 256, 0, stream>>>(pP, b_ih, b_hh, lens, cb2n, BhP, out, t);
        }
    } else {
        init_state<<<256, 256, 0, stream>>>(hbuf1, cbuf1);
        {
            int total = T_ * E_ * B_;
            gather_x<<<(total + 255) / 256, 256, 0, stream>>>(tokens, embed, x_t);
        }
        for (int t = 0; t < T_; ++t) {
            const float* h_in  = hbuf1 + (size_t)(t & 1) * 2 * H_ * B_;
            float*       h_out = hbuf1 + (size_t)((t + 1) & 1) * 2 * H_ * B_;
            lstm_step<<<512, 256, 0, stream>>>(x_t, W_ih, W_hh, b_ih, b_hh, lens,
                                               h_in, h_out, cbuf1, out, t);
        }
    }
}